// Round 11
// baseline (899.337 us; speedup 1.0000x reference)
//
#include <hip/hip_runtime.h>
#include <hip/hip_bf16.h>

typedef __attribute__((ext_vector_type(8))) short short8;
typedef __attribute__((ext_vector_type(4))) float f32x4;
typedef unsigned short u16;

#define B_N 2
#define S_N 1024
#define HID_N 2048
#define NH_N 8
#define HD_N 256
#define INTER_N 16384

#define GLB(p) ((const __attribute__((address_space(1))) void*)(p))
#define AS3(p) ((__attribute__((address_space(3))) void*)(p))

__device__ inline u16 f2b_rn(float f) {
    union { float f; unsigned int u; } x; x.f = f;
    unsigned int r = x.u + 0x7fffu + ((x.u >> 16) & 1u);
    return (u16)(r >> 16);
}
__device__ inline float b2f(u16 h) {
    union { unsigned int u; float f; } x; x.u = ((unsigned int)h) << 16;
    return x.f;
}
// gelu(tanh approx) via hw exp2/rcp: tanh(z) = 1 - 2/(e^{2z}+1)
__device__ inline float gelu_fast(float v) {
    float z = 0.7978845608028654f * (v + 0.044715f * v * v * v);
    float e = exp2f(z * 2.8853900817779268f);
    float th = 1.f - 2.f * __builtin_amdgcn_rcpf(e + 1.f);
    return 0.5f * v * (1.f + th);
}

// ---------------- fp32 -> bf16 convert (grid-stride, float4) ----------------
__global__ __launch_bounds__(256) void convert_f2b(const float* __restrict__ in,
                                                   u16* __restrict__ out, int n4) {
    int i = blockIdx.x * 256 + threadIdx.x;
    int stride = gridDim.x * 256;
    for (; i < n4; i += stride) {
        float4 v = reinterpret_cast<const float4*>(in)[i];
        u16 o[4] = { f2b_rn(v.x), f2b_rn(v.y), f2b_rn(v.z), f2b_rn(v.w) };
        reinterpret_cast<ulonglong1*>(out)[i] = *reinterpret_cast<ulonglong1*>(o);
    }
}

// ---- gate/up interleaving convert: W'[j*256+r]=wg[j*128+r], W'[j*256+128+r]=wu[j*128+r]
__global__ __launch_bounds__(256) void convert_gu(const float* __restrict__ wg,
                                                  const float* __restrict__ wu,
                                                  u16* __restrict__ out, int n4) {
    int i = blockIdx.x * 256 + threadIdx.x;
    int stride = gridDim.x * 256;
    for (; i < n4; i += stride) {
        const int e = i << 2;
        const int r = e >> 11, c = e & 2047;
        const int rg = ((r >> 7) << 8) + (r & 127);   // gate dest row
        float4 g = reinterpret_cast<const float4*>(wg)[i];
        u16 og[4] = { f2b_rn(g.x), f2b_rn(g.y), f2b_rn(g.z), f2b_rn(g.w) };
        *reinterpret_cast<ulonglong1*>(out + (size_t)rg * 2048 + c) =
            *reinterpret_cast<ulonglong1*>(og);
        float4 u = reinterpret_cast<const float4*>(wu)[i];
        u16 ou[4] = { f2b_rn(u.x), f2b_rn(u.y), f2b_rn(u.z), f2b_rn(u.w) };
        *reinterpret_cast<ulonglong1*>(out + (size_t)(rg + 128) * 2048 + c) =
            *reinterpret_cast<ulonglong1*>(ou);
    }
}

// ---------------- RMSNorm: fp32 in -> bf16 out, one block per row ----------------
__global__ __launch_bounds__(256) void rmsnorm_k(const float* __restrict__ x,
                                                 const float* __restrict__ w,
                                                 u16* __restrict__ out) {
    const int row = blockIdx.x;
    const int tid = threadIdx.x;
    const float* xr = x + (size_t)row * HID_N;
    const float4* xr4 = reinterpret_cast<const float4*>(xr);
    float4 a = xr4[tid * 2], b = xr4[tid * 2 + 1];
    float s = a.x*a.x + a.y*a.y + a.z*a.z + a.w*a.w
            + b.x*b.x + b.y*b.y + b.z*b.z + b.w*b.w;
    for (int off = 32; off > 0; off >>= 1) s += __shfl_xor(s, off, 64);
    __shared__ float red[4];
    if ((tid & 63) == 0) red[tid >> 6] = s;
    __syncthreads();
    float tot = red[0] + red[1] + red[2] + red[3];
    float inv = rsqrtf(tot * (1.0f / HID_N) + 1e-6f);
    const float4* w4 = reinterpret_cast<const float4*>(w);
    float4 wa = w4[tid * 2], wb = w4[tid * 2 + 1];
    short8 o;
    o[0] = (short)f2b_rn(a.x * inv * (1.f + wa.x));
    o[1] = (short)f2b_rn(a.y * inv * (1.f + wa.y));
    o[2] = (short)f2b_rn(a.z * inv * (1.f + wa.z));
    o[3] = (short)f2b_rn(a.w * inv * (1.f + wa.w));
    o[4] = (short)f2b_rn(b.x * inv * (1.f + wb.x));
    o[5] = (short)f2b_rn(b.y * inv * (1.f + wb.y));
    o[6] = (short)f2b_rn(b.z * inv * (1.f + wb.z));
    o[7] = (short)f2b_rn(b.w * inv * (1.f + wb.w));
    reinterpret_cast<short8*>(out + (size_t)row * HID_N)[tid] = o;
}

// ---------------- QKV post, parallel over (token, vec): grid (2048, 10) ----------------
__global__ __launch_bounds__(256) void qkv_post_k(const float* __restrict__ qkv,
                                                  const float* __restrict__ cosb,
                                                  const float* __restrict__ sinb,
                                                  const int* __restrict__ kvw,
                                                  const float* __restrict__ qn,
                                                  const float* __restrict__ kn,
                                                  u16* __restrict__ qb,
                                                  u16* __restrict__ kb,
                                                  u16* __restrict__ vt) {
    const int bs = blockIdx.x, vi = blockIdx.y;
    const int b = bs >> 10, s = bs & 1023;
    const int tid = threadIdx.x;
    const float* row = qkv + (size_t)bs * 2560;
    const int sdst = kvw[s];
    if (vi == 9) {
        vt[((size_t)(b * 256 + tid)) * 1024 + sdst] = f2b_rn(row[2304 + tid]);
        return;
    }
    __shared__ float buf[256];
    __shared__ float red[4];
    float val = row[vi * 256 + tid];
    float ss = val * val;
    for (int off = 32; off > 0; off >>= 1) ss += __shfl_xor(ss, off, 64);
    if ((tid & 63) == 0) red[tid >> 6] = ss;
    __syncthreads();
    float ms = (red[0] + red[1] + red[2] + red[3]) * (1.f / 256.f) + 1e-6f;
    const float* nw = (vi < 8) ? qn : kn;
    float nrm = val * rsqrtf(ms) * (1.f + nw[tid]);
    buf[tid] = nrm;
    __syncthreads();
    const float cv = cosb[s * 128 + (tid & 127)];
    const float sv = sinb[s * 128 + (tid & 127)];
    float o;
    if (tid < 128) o = buf[tid] * cv - buf[tid + 128] * sv;
    else           o = buf[tid - 128] * sv + buf[tid] * cv;
    if (vi < 8) qb[(((size_t)(b * 8 + vi)) * 1024 + s) * 256 + tid] = f2b_rn(o * 0.0625f);
    else        kb[((size_t)(b * 1024 + sdst)) * 256 + tid] = f2b_rn(o);
}

// ---------------- Flash attention, 4-way KV split, no barriers ----------------
// Chunks of 256 kv positions; partials combine exactly (fixed m=0).
// grid (16 qtiles, 8 heads, 8 = chunk*2+batch).
__global__ __launch_bounds__(256) void attn_k(const u16* __restrict__ qb,
                                              const u16* __restrict__ kb,
                                              const u16* __restrict__ vt,
                                              float* __restrict__ po,
                                              float* __restrict__ pl) {
    const int qt = blockIdx.x;
    const int h  = blockIdx.y;
    const int c  = blockIdx.z >> 1;
    const int b  = blockIdx.z & 1;
    if (qt < 4 * c) return;                   // block entirely before chunk
    const int tid = threadIdx.x, lane = tid & 63, wid = tid >> 6;
    const int g = lane >> 4, li = lane & 15;
    const int q0 = qt * 64 + wid * 16;
    const int kv_lo = c * 256;
    __shared__ u16 pbuf[4][16 * 32];

    short8 qf[8];
    const size_t qbase = (((size_t)(b * 8 + h)) * 1024 + q0 + li) * 256;
    #pragma unroll
    for (int kk = 0; kk < 8; ++kk)
        qf[kk] = *reinterpret_cast<const short8*>(qb + qbase + kk * 32 + g * 8);

    f32x4 o[16], o1;
    #pragma unroll
    for (int d = 0; d < 16; ++d) o[d] = f32x4{0.f, 0.f, 0.f, 0.f};
    o1 = f32x4{0.f, 0.f, 0.f, 0.f};
    short8 onesf;
    #pragma unroll
    for (int j = 0; j < 8; ++j) onesf[j] = (short)0x3F80;

    const int nt = (min(kv_lo + 256, q0 + 16) - kv_lo + 31) >> 5;
    const int prd = li * 32 + ((g * 8) ^ (((li >> 2) & 3) * 8));

    for (int t = 0; t < nt; ++t) {
        const int kv0 = kv_lo + t * 32;
        f32x4 sc[2];
        sc[0] = f32x4{0.f, 0.f, 0.f, 0.f};
        sc[1] = f32x4{0.f, 0.f, 0.f, 0.f};
        #pragma unroll
        for (int ch = 0; ch < 2; ++ch) {
            const size_t kbase = ((size_t)(b * 1024 + kv0 + ch * 16 + li)) * 256;
            #pragma unroll
            for (int kk = 0; kk < 8; ++kk) {
                short8 kf = *reinterpret_cast<const short8*>(kb + kbase + kk * 32 + g * 8);
                sc[ch] = __builtin_amdgcn_mfma_f32_16x16x32_bf16(qf[kk], kf, sc[ch], 0, 0, 0);
            }
        }
        #pragma unroll
        for (int reg = 0; reg < 4; ++reg) {
            const int qrow = q0 + g * 4 + reg;
            const int prow = g * 4 + reg;
            const int pswz = ((prow >> 2) & 3) * 8;
            #pragma unroll
            for (int ch = 0; ch < 2; ++ch) {
                const int col = kv0 + ch * 16 + li;
                float s = sc[ch][reg];
                float e = exp2f(s * 0.05770780163555854f);
                float th = 1.f - 2.f * __builtin_amdgcn_rcpf(e + 1.f);
                float pv = exp2f(th * 72.13475204444817f);
                pv = (col <= qrow) ? pv : 0.f;
                pbuf[wid][prow * 32 + ((ch * 16 + li) ^ pswz)] = f2b_rn(pv);
            }
        }
        short8 pf = *reinterpret_cast<const short8*>(&pbuf[wid][prd]);
        o1 = __builtin_amdgcn_mfma_f32_16x16x32_bf16(pf, onesf, o1, 0, 0, 0);
        #pragma unroll
        for (int dth = 0; dth < 2; ++dth) {
            short8 vf[8];
            #pragma unroll
            for (int d8 = 0; d8 < 8; ++d8) {
                const int dt = dth * 8 + d8;
                vf[d8] = *reinterpret_cast<const short8*>(
                    vt + ((size_t)(b * 256 + dt * 16 + li)) * 1024 + kv0 + g * 8);
            }
            #pragma unroll
            for (int d8 = 0; d8 < 8; ++d8)
                o[dth * 8 + d8] = __builtin_amdgcn_mfma_f32_16x16x32_bf16(pf, vf[d8], o[dth * 8 + d8], 0, 0, 0);
        }
    }
    const size_t pbase = ((size_t)((c * 2 + b) * 8 + h)) * 1024;
    #pragma unroll
    for (int reg = 0; reg < 4; ++reg) {
        const int row = q0 + g * 4 + reg;
        #pragma unroll
        for (int dt = 0; dt < 16; ++dt)
            po[(pbase + row) * 256 + dt * 16 + li] = o[dt][reg];
        if (li == 0) pl[pbase + row] = o1[reg];
    }
}

// ---------------- attention combine: out = sum_c O_c / sum_c l_c -> bf16 ----------------
__global__ __launch_bounds__(256) void attn_red_k(const float* __restrict__ po,
                                                  const float* __restrict__ pl,
                                                  u16* __restrict__ out) {
    const int gid = blockIdx.x;
    const int b = gid >> 10, s = gid & 1023;
    const int tid = threadIdx.x;
    const int h = tid >> 5, d0 = (tid & 31) * 8;
    const int cmax = s >> 8;                 // chunks 0..cmax contribute
    float l = 0.f;
    float4 a0 = float4{0.f, 0.f, 0.f, 0.f}, a1 = float4{0.f, 0.f, 0.f, 0.f};
    for (int ci = 0; ci <= cmax; ++ci) {
        const size_t r = ((size_t)((ci * 2 + b) * 8 + h)) * 1024 + s;
        l += pl[r];
        float4 b0 = *reinterpret_cast<const float4*>(po + r * 256 + d0);
        float4 b1 = *reinterpret_cast<const float4*>(po + r * 256 + d0 + 4);
        a0.x += b0.x; a0.y += b0.y; a0.z += b0.z; a0.w += b0.w;
        a1.x += b1.x; a1.y += b1.y; a1.z += b1.z; a1.w += b1.w;
    }
    const float inv = 1.f / l;
    u16 r[8] = { f2b_rn(a0.x * inv), f2b_rn(a0.y * inv), f2b_rn(a0.z * inv), f2b_rn(a0.w * inv),
                 f2b_rn(a1.x * inv), f2b_rn(a1.y * inv), f2b_rn(a1.z * inv), f2b_rn(a1.w * inv) };
    *reinterpret_cast<ulonglong2*>(out + ((size_t)gid) * 2048 + h * 256 + d0) =
        *reinterpret_cast<ulonglong2*>(r);
}

// ---------------- 128x128 bf16 GEMM, counted-vmcnt double buffer ----------------
// fences minimized (m141): only vmcnt asm + 1 sched_barrier per K-tile.
template <int EPI>
__global__ __launch_bounds__(256) void gemm_bt(const u16* __restrict__ A,
                                               const u16* __restrict__ W,
                                               const float* __restrict__ res,
                                               float* __restrict__ outf,
                                               int M, int N, int K) {
    __shared__ u16 As[2][128 * 64];
    __shared__ u16 Bs[2][128 * 64];
    const int tid = threadIdx.x, lane = tid & 63, wid = tid >> 6;
    const int g = lane >> 4, li = lane & 15;
    const int wr = wid >> 1, wc = wid & 1;
    const int m0 = blockIdx.x * 128, n0 = blockIdx.y * 128;

    f32x4 acc[4][4];
    #pragma unroll
    for (int m = 0; m < 4; ++m)
        #pragma unroll
        for (int n = 0; n < 4; ++n) acc[m][n] = f32x4{0.f, 0.f, 0.f, 0.f};

    const int lrow = lane >> 3;
    const int lcol = (lane & 7) ^ lrow;
    const u16* ga0 = A + (size_t)(m0 + wid * 32 + lrow) * K + lcol * 8;
    const u16* gb0 = W + (size_t)(n0 + wid * 32 + lrow) * K + lcol * 8;
    const int lbase = wid * 32 * 64;

    auto STAGE = [&](int buf, int k0) {
        #pragma unroll
        for (int i = 0; i < 4; ++i) {
            __builtin_amdgcn_global_load_lds(GLB(ga0 + k0 + (size_t)(i * 8) * K),
                                             AS3(&As[buf][lbase + i * 8 * 64]), 16, 0, 0);
            __builtin_amdgcn_global_load_lds(GLB(gb0 + k0 + (size_t)(i * 8) * K),
                                             AS3(&Bs[buf][lbase + i * 8 * 64]), 16, 0, 0);
        }
    };

    const int NT = K >> 6;
    STAGE(0, 0);
    int cur = 0;
    for (int t = 0; t < NT; ++t) {
        if (t + 1 < NT) {
            STAGE(cur ^ 1, (t + 1) << 6);
            asm volatile("s_waitcnt vmcnt(8)" ::: "memory");
        } else {
            asm volatile("s_waitcnt vmcnt(0)" ::: "memory");
        }
        __builtin_amdgcn_s_barrier();
        __builtin_amdgcn_sched_barrier(0);
        #pragma unroll
        for (int kh = 0; kh < 2; ++kh) {
            short8 af[4], bfr[4];
            #pragma unroll
            for (int m = 0; m < 4; ++m) {
                int rw = wr * 64 + m * 16 + li;
                int slot = (kh * 4 + g) ^ (rw & 7);
                af[m] = *reinterpret_cast<const short8*>(&As[cur][rw * 64 + slot * 8]);
            }
            #pragma unroll
            for (int n = 0; n < 4; ++n) {
                int rw = wc * 64 + n * 16 + li;
                int slot = (kh * 4 + g) ^ (rw & 7);
                bfr[n] = *reinterpret_cast<const short8*>(&Bs[cur][rw * 64 + slot * 8]);
            }
            #pragma unroll
            for (int m = 0; m < 4; ++m)
                #pragma unroll
                for (int n = 0; n < 4; ++n)
                    acc[m][n] = __builtin_amdgcn_mfma_f32_16x16x32_bf16(af[m], bfr[n], acc[m][n], 0, 0, 0);
        }
        __builtin_amdgcn_s_barrier();
        cur ^= 1;
    }

    #pragma unroll
    for (int m = 0; m < 4; ++m) {
        #pragma unroll
        for (int n = 0; n < 4; ++n) {
            #pragma unroll
            for (int reg = 0; reg < 4; ++reg) {
                int row = m0 + wr * 64 + m * 16 + g * 4 + reg;
                int col = n0 + wc * 64 + n * 16 + li;
                size_t idx = (size_t)row * N + col;
                float v = acc[m][n][reg];
                if (EPI == 0) outf[idx] = v;
                else          outf[idx] = v + res[idx];
            }
        }
    }
}

// ---------------- 256x256 bf16 GEMM, 8 waves, 8-phase counted-vmcnt pipeline ----------------
// Fences minimized (m141): no per-phase lgkmcnt(0)/sched_barrier — compiler emits precise
// partial lgkmcnt waits before MFMA use. Only vmcnt(6) + 1 sched_barrier per K-tile.
// EPI 4 = split-K f32 partial (down); EPI 5 = fused gate-up (interleaved W, gelu*up epilogue).
template <int EPI>
__global__ __launch_bounds__(512, 2) void gemm256(const u16* __restrict__ A,
                                                  const u16* __restrict__ W,
                                                  float* __restrict__ outf,
                                                  u16* __restrict__ outb,
                                                  int M, int N, int K, int kcN) {
    __shared__ u16 Als[2][256 * 64];
    __shared__ u16 Bls[2][256 * 64];
    const int tid = threadIdx.x, lane = tid & 63, wid = tid >> 6;
    const int g = lane >> 4, li = lane & 15;
    const int wm = wid >> 2, wn = wid & 3;
    const int m0 = blockIdx.y * 256, n0 = blockIdx.x * 256;

    int koff = 0, Keff = K;
    if (EPI == 4) {
        Keff = K / kcN;
        koff = blockIdx.z * Keff;
        outf += (size_t)blockIdx.z * M * N;
    }

    f32x4 acc[8][4];
    #pragma unroll
    for (int m = 0; m < 8; ++m)
        #pragma unroll
        for (int n = 0; n < 4; ++n) acc[m][n] = f32x4{0.f, 0.f, 0.f, 0.f};

    const int srcg = ((tid & 7) ^ ((tid >> 3) & 7)) * 8;
    const u16* Asrc = A + (size_t)(m0 + (tid >> 3)) * K + koff + srcg;
    const u16* Bsrc = W + (size_t)(n0 + (tid >> 3)) * K + koff + srcg;
    const int dstb = wid * 512;

    auto STAGE_A = [&](int bf, int h, int kt) {
        const int k0 = kt << 6;
        #pragma unroll
        for (int i = 0; i < 2; ++i)
            __builtin_amdgcn_global_load_lds(GLB(Asrc + (size_t)(h * 128 + i * 64) * K + k0),
                                             AS3(&Als[bf][h * 8192 + i * 4096 + dstb]), 16, 0, 0);
    };
    auto STAGE_B = [&](int bf, int h, int kt) {
        const int k0 = kt << 6;
        #pragma unroll
        for (int i = 0; i < 2; ++i)
            __builtin_amdgcn_global_load_lds(GLB(Bsrc + (size_t)(h * 128 + i * 64) * K + k0),
                                             AS3(&Bls[bf][h * 8192 + i * 4096 + dstb]), 16, 0, 0);
    };
    auto LDA = [&](short8* d, int mh, int cb) {
        #pragma unroll
        for (int m = 0; m < 4; ++m) {
            const int rw = mh * 128 + wm * 64 + m * 16 + li;
            #pragma unroll
            for (int kh = 0; kh < 2; ++kh) {
                const int slot = (kh * 4 + g) ^ (rw & 7);
                d[m * 2 + kh] = *reinterpret_cast<const short8*>(&Als[cb][rw * 64 + slot * 8]);
            }
        }
    };
    auto LDB = [&](short8* d, int nh, int cb) {
        #pragma unroll
        for (int n = 0; n < 2; ++n) {
            const int rw = nh * 128 + wn * 32 + n * 16 + li;
            #pragma unroll
            for (int kh = 0; kh < 2; ++kh) {
                const int slot = (kh * 4 + g) ^ (rw & 7);
                d[n * 2 + kh] = *reinterpret_cast<const short8*>(&Bls[cb][rw * 64 + slot * 8]);
            }
        }
    };

    short8 af[8], af2[8], bq0[4], bq1[4];
    auto MQ = [&](int mh, int nh, short8* aa, short8* bb) {
        #pragma unroll
        for (int kh = 0; kh < 2; ++kh)
            #pragma unroll
            for (int m = 0; m < 4; ++m)
                #pragma unroll
                for (int n = 0; n < 2; ++n)
                    acc[mh * 4 + m][nh * 2 + n] = __builtin_amdgcn_mfma_f32_16x16x32_bf16(
                        aa[m * 2 + kh], bb[n * 2 + kh], acc[mh * 4 + m][nh * 2 + n], 0, 0, 0);
    };

    const int NT = Keff >> 6;
    STAGE_A(0, 0, 0); STAGE_B(0, 0, 0); STAGE_B(0, 1, 0); STAGE_A(0, 1, 0);
    {
        const int t1 = (1 < NT) ? 1 : NT - 1;
        STAGE_A(1, 0, t1); STAGE_B(1, 0, t1); STAGE_B(1, 1, t1);
    }
    asm volatile("s_waitcnt vmcnt(6)" ::: "memory");
    __builtin_amdgcn_s_barrier();
    __builtin_amdgcn_sched_barrier(0);
    LDA(af2, 0, 0);

    int cur = 0;
    for (int t = 0; t < NT; ++t) {
        const int tp1 = (t + 1 < NT) ? t + 1 : NT - 1;
        const int tp2 = (t + 2 < NT) ? t + 2 : NT - 1;
        // P1: (0,0) w/ af2; reads B-h0; stage A-h1(t+1) -> cur^1
        LDB(bq0, 0, cur);
        STAGE_A(cur ^ 1, 1, tp1);
        __builtin_amdgcn_s_barrier();
        __builtin_amdgcn_s_setprio(1);
        MQ(0, 0, af2, bq0);
        __builtin_amdgcn_s_setprio(0);
        __builtin_amdgcn_s_barrier();
        // P2: (0,1) w/ af2; reads B-h1; stage A-h0(t+2) -> cur
        LDB(bq1, 1, cur);
        STAGE_A(cur, 0, tp2);
        __builtin_amdgcn_s_barrier();
        __builtin_amdgcn_s_setprio(1);
        MQ(0, 1, af2, bq1);
        __builtin_amdgcn_s_setprio(0);
        __builtin_amdgcn_s_barrier();
        // P3: (1,1); reads A-h1; stage B-h0(t+2) -> cur
        LDA(af, 1, cur);
        STAGE_B(cur, 0, tp2);
        __builtin_amdgcn_s_barrier();
        __builtin_amdgcn_s_setprio(1);
        MQ(1, 1, af, bq1);
        __builtin_amdgcn_s_setprio(0);
        __builtin_amdgcn_s_barrier();
        // P4: (1,0); stage B-h1(t+2) -> cur; vmcnt(6)+barrier certifies t+1; prefetch af2
        STAGE_B(cur, 1, tp2);
        __builtin_amdgcn_s_setprio(1);
        MQ(1, 0, af, bq0);
        __builtin_amdgcn_s_setprio(0);
        asm volatile("s_waitcnt vmcnt(6)" ::: "memory");
        __builtin_amdgcn_s_barrier();
        __builtin_amdgcn_sched_barrier(0);
        LDA(af2, 0, cur ^ 1);
        cur ^= 1;
    }

    if (EPI == 5) {
        // fused epilogue: acc[mg][n] = gate cols, acc[mg][n+2] = up cols (same output col)
        #pragma unroll
        for (int mg = 0; mg < 8; ++mg) {
            const int mh = mg >> 2, m = mg & 3;
            #pragma unroll
            for (int n = 0; n < 2; ++n) {
                const int col = (n0 >> 1) + wn * 32 + n * 16 + li;
                #pragma unroll
                for (int reg = 0; reg < 4; ++reg) {
                    const int row = m0 + mh * 128 + wm * 64 + m * 16 + g * 4 + reg;
                    float gt = gelu_fast(acc[mg][n][reg]);
                    float up = acc[mg][n + 2][reg];
                    outb[(size_t)row * INTER_N + col] = f2b_rn(gt * up);
                }
            }
        }
    } else {
        #pragma unroll
        for (int mg = 0; mg < 8; ++mg) {
            const int mh = mg >> 2, m = mg & 3;
            #pragma unroll
            for (int ng = 0; ng < 4; ++ng) {
                const int nh = ng >> 1, n = ng & 1;
                #pragma unroll
                for (int reg = 0; reg < 4; ++reg) {
                    const int row = m0 + mh * 128 + wm * 64 + m * 16 + g * 4 + reg;
                    const int col = n0 + nh * 128 + wn * 32 + n * 16 + li;
                    outf[(size_t)row * N + col] = acc[mg][ng][reg];
                }
            }
        }
    }
}

// ---------------- split-K reduce: out = res + p0+p1+p2+p3 ----------------
__global__ __launch_bounds__(256) void reduce4_k(const float* __restrict__ part,
                                                 const float* __restrict__ res,
                                                 float* __restrict__ out, int n4) {
    int i = blockIdx.x * 256 + threadIdx.x;
    int stride = gridDim.x * 256;
    const size_t ps = (size_t)HID_N * B_N * S_N / 4;
    const float4* p4 = reinterpret_cast<const float4*>(part);
    const float4* r4 = reinterpret_cast<const float4*>(res);
    float4* o4 = reinterpret_cast<float4*>(out);
    for (; i < n4; i += stride) {
        float4 a = p4[i], b = p4[i + ps], c = p4[i + 2 * ps], d = p4[i + 3 * ps];
        float4 r = r4[i];
        float4 o;
        o.x = r.x + a.x + b.x + c.x + d.x;
        o.y = r.y + a.y + b.y + c.y + d.y;
        o.z = r.z + a.z + b.z + c.z + d.z;
        o.w = r.w + a.w + b.w + c.w + d.w;
        o4[i] = o;
    }
}

extern "C" void kernel_launch(void* const* d_in, const int* in_sizes, int n_in,
                              void* d_out, int out_size, void* d_ws, size_t ws_size,
                              hipStream_t stream) {
    (void)in_sizes; (void)n_in; (void)out_size; (void)ws_size;
    const float* hs     = (const float*)d_in[0];
    const float* cosb   = (const float*)d_in[1];
    const float* sinb   = (const float*)d_in[2];
    const int*   kvw    = (const int*)d_in[3];
    const float* wqkv   = (const float*)d_in[7];
    const float* wo     = (const float*)d_in[8];
    const float* wg     = (const float*)d_in[9];
    const float* wu     = (const float*)d_in[10];
    const float* wd     = (const float*)d_in[11];
    const float* ln_in  = (const float*)d_in[12];
    const float* ln_post= (const float*)d_in[13];
    const float* qn     = (const float*)d_in[14];
    const float* kn     = (const float*)d_in[15];
    float* out = (float*)d_out;

    char* p = (char*)d_ws;
    auto alloc = [&](size_t bytes) {
        char* r = p;
        p += (bytes + 255) & ~(size_t)255;
        return r;
    };
    u16* wqkv_b = (u16*)alloc(2560ull * 2048 * 2);
    u16* wo_b   = (u16*)alloc(2048ull * 2048 * 2);
    u16* wgu_b  = (u16*)alloc(32768ull * 2048 * 2);   // interleaved gate/up
    u16* wd_b   = (u16*)alloc(2048ull * 16384 * 2);
    u16* xn     = (u16*)alloc(2048ull * 2048 * 2);
    float* qkvf = (float*)alloc(2048ull * 2560 * 4);
    u16* qbuf   = (u16*)alloc(2ull * 8 * 1024 * 256 * 2);
    u16* kbuf   = (u16*)alloc(2ull * 1024 * 256 * 2);
    u16* vtbuf  = (u16*)alloc(2ull * 256 * 1024 * 2);
    u16* attn_o = (u16*)alloc(2048ull * 2048 * 2);
    float* hbuf = (float*)alloc(2048ull * 2048 * 4);
    u16* x2     = (u16*)alloc(2048ull * 2048 * 2);
    u16* actb   = (u16*)alloc(2048ull * 16384 * 2);
    float* po   = (float*)alloc(8ull * 8 * 1024 * 256 * 4);   // 4 chunks x 2 batch
    float* plse = (float*)alloc(8ull * 8 * 1024 * 4);
    float* partials = (float*)d_ws;  // overlays dead weight-convert buffers

    auto conv = [&](const float* src, u16* dst, long n) {
        int n4 = (int)(n / 4);
        long blk = (n4 + 255) / 256;
        if (blk > 4096) blk = 4096;
        convert_f2b<<<dim3((unsigned)blk), dim3(256), 0, stream>>>(src, dst, n4);
    };
    conv(wqkv, wqkv_b, 2560l * 2048);
    conv(wo,   wo_b,   2048l * 2048);
    convert_gu<<<dim3(4096), dim3(256), 0, stream>>>(wg, wu, wgu_b, 8388608);
    conv(wd,   wd_b,   2048l * 16384);

    rmsnorm_k<<<dim3(2048), dim3(256), 0, stream>>>(hs, ln_in, xn);
    gemm_bt<0><<<dim3(16, 20), dim3(256), 0, stream>>>(xn, wqkv_b, nullptr,
                                                       qkvf, 2048, 2560, 2048);
    qkv_post_k<<<dim3(2048, 10), dim3(256), 0, stream>>>(qkvf, cosb, sinb, kvw, qn, kn,
                                                         qbuf, kbuf, vtbuf);
    attn_k<<<dim3(16, 8, 8), dim3(256), 0, stream>>>(qbuf, kbuf, vtbuf, po, plse);
    attn_red_k<<<dim3(2048), dim3(256), 0, stream>>>(po, plse, attn_o);
    gemm_bt<1><<<dim3(16, 16), dim3(256), 0, stream>>>(attn_o, wo_b, hs,
                                                       hbuf, 2048, 2048, 2048);
    rmsnorm_k<<<dim3(2048), dim3(256), 0, stream>>>(hbuf, ln_post, x2);
    // fused gate-up: grid x = n-tile over 32768 interleaved rows (128 tiles), y = m (8)
    gemm256<5><<<dim3(128, 8), dim3(512), 0, stream>>>(x2, wgu_b, nullptr, actb,
                                                       2048, 16384, 2048, 1);
    // down: split-K=4 partials, then reduce with residual
    gemm256<4><<<dim3(8, 8, 4), dim3(512), 0, stream>>>(actb, wd_b, partials, nullptr,
                                                        2048, 2048, 16384, 4);
    reduce4_k<<<dim3(2048), dim3(256), 0, stream>>>(partials, hbuf, out, 1048576);
}

// Round 12
// 810.832 us; speedup vs baseline: 1.1092x; 1.1092x over previous
//
#include <hip/hip_runtime.h>
#include <hip/hip_bf16.h>

typedef __attribute__((ext_vector_type(8))) short short8;
typedef __attribute__((ext_vector_type(4))) float f32x4;
typedef unsigned short u16;

#define B_N 2
#define S_N 1024
#define HID_N 2048
#define NH_N 8
#define HD_N 256
#define INTER_N 16384

#define GLB(p) ((const __attribute__((address_space(1))) void*)(p))
#define AS3(p) ((__attribute__((address_space(3))) void*)(p))

__device__ inline u16 f2b_rn(float f) {
    union { float f; unsigned int u; } x; x.f = f;
    unsigned int r = x.u + 0x7fffu + ((x.u >> 16) & 1u);
    return (u16)(r >> 16);
}
__device__ inline float b2f(u16 h) {
    union { unsigned int u; float f; } x; x.u = ((unsigned int)h) << 16;
    return x.f;
}
// gelu(tanh approx) via hw exp2/rcp: tanh(z) = 1 - 2/(e^{2z}+1)
__device__ inline float gelu_fast(float v) {
    float z = 0.7978845608028654f * (v + 0.044715f * v * v * v);
    float e = exp2f(z * 2.8853900817779268f);
    float th = 1.f - 2.f * __builtin_amdgcn_rcpf(e + 1.f);
    return 0.5f * v * (1.f + th);
}

// ---------------- fp32 -> bf16 convert (grid-stride, float4) ----------------
__global__ __launch_bounds__(256) void convert_f2b(const float* __restrict__ in,
                                                   u16* __restrict__ out, int n4) {
    int i = blockIdx.x * 256 + threadIdx.x;
    int stride = gridDim.x * 256;
    for (; i < n4; i += stride) {
        float4 v = reinterpret_cast<const float4*>(in)[i];
        u16 o[4] = { f2b_rn(v.x), f2b_rn(v.y), f2b_rn(v.z), f2b_rn(v.w) };
        reinterpret_cast<ulonglong1*>(out)[i] = *reinterpret_cast<ulonglong1*>(o);
    }
}

// ---- gate/up interleave, 32-row granularity:
// W'[(r>>5)*64 + (r&31)] = wg[r],  W'[(r>>5)*64 + 32 + (r&31)] = wu[r]
__global__ __launch_bounds__(256) void convert_gu(const float* __restrict__ wg,
                                                  const float* __restrict__ wu,
                                                  u16* __restrict__ out, int n4) {
    int i = blockIdx.x * 256 + threadIdx.x;
    int stride = gridDim.x * 256;
    for (; i < n4; i += stride) {
        const int e = i << 2;
        const int r = e >> 11, c = e & 2047;
        const int rg = ((r >> 5) << 6) + (r & 31);
        float4 g = reinterpret_cast<const float4*>(wg)[i];
        u16 og[4] = { f2b_rn(g.x), f2b_rn(g.y), f2b_rn(g.z), f2b_rn(g.w) };
        *reinterpret_cast<ulonglong1*>(out + (size_t)rg * 2048 + c) =
            *reinterpret_cast<ulonglong1*>(og);
        float4 u = reinterpret_cast<const float4*>(wu)[i];
        u16 ou[4] = { f2b_rn(u.x), f2b_rn(u.y), f2b_rn(u.z), f2b_rn(u.w) };
        *reinterpret_cast<ulonglong1*>(out + (size_t)(rg + 32) * 2048 + c) =
            *reinterpret_cast<ulonglong1*>(ou);
    }
}

// ---------------- RMSNorm: fp32 in -> bf16 out, one block per row ----------------
__global__ __launch_bounds__(256) void rmsnorm_k(const float* __restrict__ x,
                                                 const float* __restrict__ w,
                                                 u16* __restrict__ out) {
    const int row = blockIdx.x;
    const int tid = threadIdx.x;
    const float* xr = x + (size_t)row * HID_N;
    const float4* xr4 = reinterpret_cast<const float4*>(xr);
    float4 a = xr4[tid * 2], b = xr4[tid * 2 + 1];
    float s = a.x*a.x + a.y*a.y + a.z*a.z + a.w*a.w
            + b.x*b.x + b.y*b.y + b.z*b.z + b.w*b.w;
    for (int off = 32; off > 0; off >>= 1) s += __shfl_xor(s, off, 64);
    __shared__ float red[4];
    if ((tid & 63) == 0) red[tid >> 6] = s;
    __syncthreads();
    float tot = red[0] + red[1] + red[2] + red[3];
    float inv = rsqrtf(tot * (1.0f / HID_N) + 1e-6f);
    const float4* w4 = reinterpret_cast<const float4*>(w);
    float4 wa = w4[tid * 2], wb = w4[tid * 2 + 1];
    short8 o;
    o[0] = (short)f2b_rn(a.x * inv * (1.f + wa.x));
    o[1] = (short)f2b_rn(a.y * inv * (1.f + wa.y));
    o[2] = (short)f2b_rn(a.z * inv * (1.f + wa.z));
    o[3] = (short)f2b_rn(a.w * inv * (1.f + wa.w));
    o[4] = (short)f2b_rn(b.x * inv * (1.f + wb.x));
    o[5] = (short)f2b_rn(b.y * inv * (1.f + wb.y));
    o[6] = (short)f2b_rn(b.z * inv * (1.f + wb.z));
    o[7] = (short)f2b_rn(b.w * inv * (1.f + wb.w));
    reinterpret_cast<short8*>(out + (size_t)row * HID_N)[tid] = o;
}

// ---------------- QKV post, parallel over (token, vec): grid (2048, 10) ----------------
__global__ __launch_bounds__(256) void qkv_post_k(const float* __restrict__ qkv,
                                                  const float* __restrict__ cosb,
                                                  const float* __restrict__ sinb,
                                                  const int* __restrict__ kvw,
                                                  const float* __restrict__ qn,
                                                  const float* __restrict__ kn,
                                                  u16* __restrict__ qb,
                                                  u16* __restrict__ kb,
                                                  u16* __restrict__ vt) {
    const int bs = blockIdx.x, vi = blockIdx.y;
    const int b = bs >> 10, s = bs & 1023;
    const int tid = threadIdx.x;
    const float* row = qkv + (size_t)bs * 2560;
    const int sdst = kvw[s];
    if (vi == 9) {
        vt[((size_t)(b * 256 + tid)) * 1024 + sdst] = f2b_rn(row[2304 + tid]);
        return;
    }
    __shared__ float buf[256];
    __shared__ float red[4];
    float val = row[vi * 256 + tid];
    float ss = val * val;
    for (int off = 32; off > 0; off >>= 1) ss += __shfl_xor(ss, off, 64);
    if ((tid & 63) == 0) red[tid >> 6] = ss;
    __syncthreads();
    float ms = (red[0] + red[1] + red[2] + red[3]) * (1.f / 256.f) + 1e-6f;
    const float* nw = (vi < 8) ? qn : kn;
    float nrm = val * rsqrtf(ms) * (1.f + nw[tid]);
    buf[tid] = nrm;
    __syncthreads();
    const float cv = cosb[s * 128 + (tid & 127)];
    const float sv = sinb[s * 128 + (tid & 127)];
    float o;
    if (tid < 128) o = buf[tid] * cv - buf[tid + 128] * sv;
    else           o = buf[tid - 128] * sv + buf[tid] * cv;
    if (vi < 8) qb[(((size_t)(b * 8 + vi)) * 1024 + s) * 256 + tid] = f2b_rn(o * 0.0625f);
    else        kb[((size_t)(b * 1024 + sdst)) * 256 + tid] = f2b_rn(o);
}

// ---------------- Flash attention, 4-way KV split, no barriers ----------------
__global__ __launch_bounds__(256) void attn_k(const u16* __restrict__ qb,
                                              const u16* __restrict__ kb,
                                              const u16* __restrict__ vt,
                                              float* __restrict__ po,
                                              float* __restrict__ pl) {
    const int qt = blockIdx.x;
    const int h  = blockIdx.y;
    const int c  = blockIdx.z >> 1;
    const int b  = blockIdx.z & 1;
    if (qt < 4 * c) return;
    const int tid = threadIdx.x, lane = tid & 63, wid = tid >> 6;
    const int g = lane >> 4, li = lane & 15;
    const int q0 = qt * 64 + wid * 16;
    const int kv_lo = c * 256;
    __shared__ u16 pbuf[4][16 * 32];

    short8 qf[8];
    const size_t qbase = (((size_t)(b * 8 + h)) * 1024 + q0 + li) * 256;
    #pragma unroll
    for (int kk = 0; kk < 8; ++kk)
        qf[kk] = *reinterpret_cast<const short8*>(qb + qbase + kk * 32 + g * 8);

    f32x4 o[16], o1;
    #pragma unroll
    for (int d = 0; d < 16; ++d) o[d] = f32x4{0.f, 0.f, 0.f, 0.f};
    o1 = f32x4{0.f, 0.f, 0.f, 0.f};
    short8 onesf;
    #pragma unroll
    for (int j = 0; j < 8; ++j) onesf[j] = (short)0x3F80;

    const int nt = (min(kv_lo + 256, q0 + 16) - kv_lo + 31) >> 5;
    const int prd = li * 32 + ((g * 8) ^ (((li >> 2) & 3) * 8));

    for (int t = 0; t < nt; ++t) {
        const int kv0 = kv_lo + t * 32;
        f32x4 sc[2];
        sc[0] = f32x4{0.f, 0.f, 0.f, 0.f};
        sc[1] = f32x4{0.f, 0.f, 0.f, 0.f};
        #pragma unroll
        for (int ch = 0; ch < 2; ++ch) {
            const size_t kbase = ((size_t)(b * 1024 + kv0 + ch * 16 + li)) * 256;
            #pragma unroll
            for (int kk = 0; kk < 8; ++kk) {
                short8 kf = *reinterpret_cast<const short8*>(kb + kbase + kk * 32 + g * 8);
                sc[ch] = __builtin_amdgcn_mfma_f32_16x16x32_bf16(qf[kk], kf, sc[ch], 0, 0, 0);
            }
        }
        #pragma unroll
        for (int reg = 0; reg < 4; ++reg) {
            const int qrow = q0 + g * 4 + reg;
            const int prow = g * 4 + reg;
            const int pswz = ((prow >> 2) & 3) * 8;
            #pragma unroll
            for (int ch = 0; ch < 2; ++ch) {
                const int col = kv0 + ch * 16 + li;
                float s = sc[ch][reg];
                float e = exp2f(s * 0.05770780163555854f);
                float th = 1.f - 2.f * __builtin_amdgcn_rcpf(e + 1.f);
                float pv = exp2f(th * 72.13475204444817f);
                pv = (col <= qrow) ? pv : 0.f;
                pbuf[wid][prow * 32 + ((ch * 16 + li) ^ pswz)] = f2b_rn(pv);
            }
        }
        short8 pf = *reinterpret_cast<const short8*>(&pbuf[wid][prd]);
        o1 = __builtin_amdgcn_mfma_f32_16x16x32_bf16(pf, onesf, o1, 0, 0, 0);
        #pragma unroll
        for (int dth = 0; dth < 2; ++dth) {
            short8 vf[8];
            #pragma unroll
            for (int d8 = 0; d8 < 8; ++d8) {
                const int dt = dth * 8 + d8;
                vf[d8] = *reinterpret_cast<const short8*>(
                    vt + ((size_t)(b * 256 + dt * 16 + li)) * 1024 + kv0 + g * 8);
            }
            #pragma unroll
            for (int d8 = 0; d8 < 8; ++d8)
                o[dth * 8 + d8] = __builtin_amdgcn_mfma_f32_16x16x32_bf16(pf, vf[d8], o[dth * 8 + d8], 0, 0, 0);
        }
    }
    const size_t pbase = ((size_t)((c * 2 + b) * 8 + h)) * 1024;
    #pragma unroll
    for (int reg = 0; reg < 4; ++reg) {
        const int row = q0 + g * 4 + reg;
        #pragma unroll
        for (int dt = 0; dt < 16; ++dt)
            po[(pbase + row) * 256 + dt * 16 + li] = o[dt][reg];
        if (li == 0) pl[pbase + row] = o1[reg];
    }
}

// ---------------- attention combine: out = sum_c O_c / sum_c l_c -> bf16 ----------------
__global__ __launch_bounds__(256) void attn_red_k(const float* __restrict__ po,
                                                  const float* __restrict__ pl,
                                                  u16* __restrict__ out) {
    const int gid = blockIdx.x;
    const int b = gid >> 10, s = gid & 1023;
    const int tid = threadIdx.x;
    const int h = tid >> 5, d0 = (tid & 31) * 8;
    const int cmax = s >> 8;
    float l = 0.f;
    float4 a0 = float4{0.f, 0.f, 0.f, 0.f}, a1 = float4{0.f, 0.f, 0.f, 0.f};
    for (int ci = 0; ci <= cmax; ++ci) {
        const size_t r = ((size_t)((ci * 2 + b) * 8 + h)) * 1024 + s;
        l += pl[r];
        float4 b0 = *reinterpret_cast<const float4*>(po + r * 256 + d0);
        float4 b1 = *reinterpret_cast<const float4*>(po + r * 256 + d0 + 4);
        a0.x += b0.x; a0.y += b0.y; a0.z += b0.z; a0.w += b0.w;
        a1.x += b1.x; a1.y += b1.y; a1.z += b1.z; a1.w += b1.w;
    }
    const float inv = 1.f / l;
    u16 r[8] = { f2b_rn(a0.x * inv), f2b_rn(a0.y * inv), f2b_rn(a0.z * inv), f2b_rn(a0.w * inv),
                 f2b_rn(a1.x * inv), f2b_rn(a1.y * inv), f2b_rn(a1.z * inv), f2b_rn(a1.w * inv) };
    *reinterpret_cast<ulonglong2*>(out + ((size_t)gid) * 2048 + h * 256 + d0) =
        *reinterpret_cast<ulonglong2*>(r);
}

// ---------------- 128x128 bf16 GEMM, counted-vmcnt double buffer ----------------
template <int EPI>
__global__ __launch_bounds__(256) void gemm_bt(const u16* __restrict__ A,
                                               const u16* __restrict__ W,
                                               const float* __restrict__ res,
                                               float* __restrict__ outf,
                                               int M, int N, int K) {
    __shared__ u16 As[2][128 * 64];
    __shared__ u16 Bs[2][128 * 64];
    const int tid = threadIdx.x, lane = tid & 63, wid = tid >> 6;
    const int g = lane >> 4, li = lane & 15;
    const int wr = wid >> 1, wc = wid & 1;
    const int m0 = blockIdx.x * 128, n0 = blockIdx.y * 128;

    f32x4 acc[4][4];
    #pragma unroll
    for (int m = 0; m < 4; ++m)
        #pragma unroll
        for (int n = 0; n < 4; ++n) acc[m][n] = f32x4{0.f, 0.f, 0.f, 0.f};

    const int lrow = lane >> 3;
    const int lcol = (lane & 7) ^ lrow;
    const u16* ga0 = A + (size_t)(m0 + wid * 32 + lrow) * K + lcol * 8;
    const u16* gb0 = W + (size_t)(n0 + wid * 32 + lrow) * K + lcol * 8;
    const int lbase = wid * 32 * 64;

    auto STAGE = [&](int buf, int k0) {
        #pragma unroll
        for (int i = 0; i < 4; ++i) {
            __builtin_amdgcn_global_load_lds(GLB(ga0 + k0 + (size_t)(i * 8) * K),
                                             AS3(&As[buf][lbase + i * 8 * 64]), 16, 0, 0);
            __builtin_amdgcn_global_load_lds(GLB(gb0 + k0 + (size_t)(i * 8) * K),
                                             AS3(&Bs[buf][lbase + i * 8 * 64]), 16, 0, 0);
        }
    };

    const int NT = K >> 6;
    STAGE(0, 0);
    int cur = 0;
    for (int t = 0; t < NT; ++t) {
        if (t + 1 < NT) {
            STAGE(cur ^ 1, (t + 1) << 6);
            asm volatile("s_waitcnt vmcnt(8)" ::: "memory");
        } else {
            asm volatile("s_waitcnt vmcnt(0)" ::: "memory");
        }
        __builtin_amdgcn_s_barrier();
        __builtin_amdgcn_sched_barrier(0);
        #pragma unroll
        for (int kh = 0; kh < 2; ++kh) {
            short8 af[4], bfr[4];
            #pragma unroll
            for (int m = 0; m < 4; ++m) {
                int rw = wr * 64 + m * 16 + li;
                int slot = (kh * 4 + g) ^ (rw & 7);
                af[m] = *reinterpret_cast<const short8*>(&As[cur][rw * 64 + slot * 8]);
            }
            #pragma unroll
            for (int n = 0; n < 4; ++n) {
                int rw = wc * 64 + n * 16 + li;
                int slot = (kh * 4 + g) ^ (rw & 7);
                bfr[n] = *reinterpret_cast<const short8*>(&Bs[cur][rw * 64 + slot * 8]);
            }
            #pragma unroll
            for (int m = 0; m < 4; ++m)
                #pragma unroll
                for (int n = 0; n < 4; ++n)
                    acc[m][n] = __builtin_amdgcn_mfma_f32_16x16x32_bf16(af[m], bfr[n], acc[m][n], 0, 0, 0);
        }
        __builtin_amdgcn_s_barrier();
        cur ^= 1;
    }

    #pragma unroll
    for (int m = 0; m < 4; ++m) {
        #pragma unroll
        for (int n = 0; n < 4; ++n) {
            #pragma unroll
            for (int reg = 0; reg < 4; ++reg) {
                int row = m0 + wr * 64 + m * 16 + g * 4 + reg;
                int col = n0 + wc * 64 + n * 16 + li;
                size_t idx = (size_t)row * N + col;
                float v = acc[m][n][reg];
                if (EPI == 0) outf[idx] = v;
                else          outf[idx] = v + res[idx];
            }
        }
    }
}

// ---------------- 256x256 bf16 GEMM, 16 waves (1024 thr), 2-phase counted vmcnt ----------
// Per-wave output 64x64 (acc=64 VGPR) -> 4 waves/SIMD occupancy (vs 2 before).
// EPI 4 = split-K f32 partial (down); EPI 5 = fused gate-up (32-row interleaved W,
// wave-local gelu(gate)*up epilogue: gate frag n, up frag n+2, n in {0,1}).
template <int EPI>
__global__ __launch_bounds__(1024) void gemm256(const u16* __restrict__ A,
                                                const u16* __restrict__ W,
                                                float* __restrict__ outf,
                                                u16* __restrict__ outb,
                                                int M, int N, int K, int kcN) {
    __shared__ u16 Als[2][256 * 64];
    __shared__ u16 Bls[2][256 * 64];
    const int tid = threadIdx.x, lane = tid & 63, wid = tid >> 6;  // 16 waves
    const int g = lane >> 4, li = lane & 15;
    const int wm = wid >> 2, wn = wid & 3;                          // 4 x 4
    const int m0 = blockIdx.y * 256, n0 = blockIdx.x * 256;

    int koff = 0, Keff = K;
    if (EPI == 4) {
        Keff = K / kcN;
        koff = blockIdx.z * Keff;
        outf += (size_t)blockIdx.z * M * N;
    }

    f32x4 acc[4][4];
    #pragma unroll
    for (int m = 0; m < 4; ++m)
        #pragma unroll
        for (int n = 0; n < 4; ++n) acc[m][n] = f32x4{0.f, 0.f, 0.f, 0.f};

    // staging: 2 issues per matrix per K-tile; thread t -> row (t>>3) + i*128,
    // source granule inverse-XOR-swizzled; linear LDS dest (wave rows = wid*8).
    const int trow = tid >> 3;                       // 0..127
    const int sgr = ((tid & 7) ^ (trow & 7)) * 8;
    const u16* Asrc = A + (size_t)(m0 + trow) * K + koff + sgr;
    const u16* Bsrc = W + (size_t)(n0 + trow) * K + koff + sgr;
    const int dstb = wid * 512;

    auto STAGE = [&](int bf, int kt) {
        const int k0 = kt << 6;
        #pragma unroll
        for (int i = 0; i < 2; ++i) {
            __builtin_amdgcn_global_load_lds(GLB(Asrc + (size_t)(i * 128) * K + k0),
                                             AS3(&Als[bf][i * 8192 + dstb]), 16, 0, 0);
            __builtin_amdgcn_global_load_lds(GLB(Bsrc + (size_t)(i * 128) * K + k0),
                                             AS3(&Bls[bf][i * 8192 + dstb]), 16, 0, 0);
        }
    };

    const int NT = Keff >> 6;
    STAGE(0, 0);
    int cur = 0;
    for (int t = 0; t < NT; ++t) {
        if (t + 1 < NT) {
            STAGE(cur ^ 1, t + 1);
            asm volatile("s_waitcnt vmcnt(4)" ::: "memory");
        } else {
            asm volatile("s_waitcnt vmcnt(0)" ::: "memory");
        }
        __builtin_amdgcn_s_barrier();
        __builtin_amdgcn_sched_barrier(0);
        #pragma unroll
        for (int kh = 0; kh < 2; ++kh) {
            short8 af[4], bfr[4];
            #pragma unroll
            for (int m = 0; m < 4; ++m) {
                const int rw = wm * 64 + m * 16 + li;
                const int slot = (kh * 4 + g) ^ (rw & 7);
                af[m] = *reinterpret_cast<const short8*>(&Als[cur][rw * 64 + slot * 8]);
            }
            #pragma unroll
            for (int n = 0; n < 4; ++n) {
                const int rw = wn * 64 + n * 16 + li;
                const int slot = (kh * 4 + g) ^ (rw & 7);
                bfr[n] = *reinterpret_cast<const short8*>(&Bls[cur][rw * 64 + slot * 8]);
            }
            #pragma unroll
            for (int m = 0; m < 4; ++m)
                #pragma unroll
                for (int n = 0; n < 4; ++n)
                    acc[m][n] = __builtin_amdgcn_mfma_f32_16x16x32_bf16(af[m], bfr[n], acc[m][n], 0, 0, 0);
        }
        __builtin_amdgcn_s_barrier();
        cur ^= 1;
    }

    if (EPI == 5) {
        // interleaved W: 64-row blocks = [32 gate][32 up] for the same 32 out-cols.
        // wave covers one 64-block (wn); gate frag n in {0,1}, up frag n+2.
        #pragma unroll
        for (int m = 0; m < 4; ++m) {
            #pragma unroll
            for (int n = 0; n < 2; ++n) {
                const int col = (n0 >> 1) + wn * 32 + n * 16 + li;
                #pragma unroll
                for (int reg = 0; reg < 4; ++reg) {
                    const int row = m0 + wm * 64 + m * 16 + g * 4 + reg;
                    float gt = gelu_fast(acc[m][n][reg]);
                    float up = acc[m][n + 2][reg];
                    outb[(size_t)row * INTER_N + col] = f2b_rn(gt * up);
                }
            }
        }
    } else {
        #pragma unroll
        for (int m = 0; m < 4; ++m) {
            #pragma unroll
            for (int n = 0; n < 4; ++n) {
                #pragma unroll
                for (int reg = 0; reg < 4; ++reg) {
                    const int row = m0 + wm * 64 + m * 16 + g * 4 + reg;
                    const int col = n0 + wn * 64 + n * 16 + li;
                    outf[(size_t)row * N + col] = acc[m][n][reg];
                }
            }
        }
    }
}

// ---------------- split-K reduce: out = res + p0+p1+p2+p3 ----------------
__global__ __launch_bounds__(256) void reduce4_k(const float* __restrict__ part,
                                                 const float* __restrict__ res,
                                                 float* __restrict__ out, int n4) {
    int i = blockIdx.x * 256 + threadIdx.x;
    int stride = gridDim.x * 256;
    const size_t ps = (size_t)HID_N * B_N * S_N / 4;
    const float4* p4 = reinterpret_cast<const float4*>(part);
    const float4* r4 = reinterpret_cast<const float4*>(res);
    float4* o4 = reinterpret_cast<float4*>(out);
    for (; i < n4; i += stride) {
        float4 a = p4[i], b = p4[i + ps], c = p4[i + 2 * ps], d = p4[i + 3 * ps];
        float4 r = r4[i];
        float4 o;
        o.x = r.x + a.x + b.x + c.x + d.x;
        o.y = r.y + a.y + b.y + c.y + d.y;
        o.z = r.z + a.z + b.z + c.z + d.z;
        o.w = r.w + a.w + b.w + c.w + d.w;
        o4[i] = o;
    }
}

extern "C" void kernel_launch(void* const* d_in, const int* in_sizes, int n_in,
                              void* d_out, int out_size, void* d_ws, size_t ws_size,
                              hipStream_t stream) {
    (void)in_sizes; (void)n_in; (void)out_size; (void)ws_size;
    const float* hs     = (const float*)d_in[0];
    const float* cosb   = (const float*)d_in[1];
    const float* sinb   = (const float*)d_in[2];
    const int*   kvw    = (const int*)d_in[3];
    const float* wqkv   = (const float*)d_in[7];
    const float* wo     = (const float*)d_in[8];
    const float* wg     = (const float*)d_in[9];
    const float* wu     = (const float*)d_in[10];
    const float* wd     = (const float*)d_in[11];
    const float* ln_in  = (const float*)d_in[12];
    const float* ln_post= (const float*)d_in[13];
    const float* qn     = (const float*)d_in[14];
    const float* kn     = (const float*)d_in[15];
    float* out = (float*)d_out;

    char* p = (char*)d_ws;
    auto alloc = [&](size_t bytes) {
        char* r = p;
        p += (bytes + 255) & ~(size_t)255;
        return r;
    };
    u16* wqkv_b = (u16*)alloc(2560ull * 2048 * 2);
    u16* wo_b   = (u16*)alloc(2048ull * 2048 * 2);
    u16* wgu_b  = (u16*)alloc(32768ull * 2048 * 2);   // interleaved gate/up (32-row)
    u16* wd_b   = (u16*)alloc(2048ull * 16384 * 2);
    u16* xn     = (u16*)alloc(2048ull * 2048 * 2);
    float* qkvf = (float*)alloc(2048ull * 2560 * 4);
    u16* qbuf   = (u16*)alloc(2ull * 8 * 1024 * 256 * 2);
    u16* kbuf   = (u16*)alloc(2ull * 1024 * 256 * 2);
    u16* vtbuf  = (u16*)alloc(2ull * 256 * 1024 * 2);
    u16* attn_o = (u16*)alloc(2048ull * 2048 * 2);
    float* hbuf = (float*)alloc(2048ull * 2048 * 4);
    u16* x2     = (u16*)alloc(2048ull * 2048 * 2);
    u16* actb   = (u16*)alloc(2048ull * 16384 * 2);
    float* po   = (float*)alloc(8ull * 8 * 1024 * 256 * 4);   // 4 chunks x 2 batch
    float* plse = (float*)alloc(8ull * 8 * 1024 * 4);
    float* partials = (float*)d_ws;  // overlays dead weight-convert buffers

    auto conv = [&](const float* src, u16* dst, long n) {
        int n4 = (int)(n / 4);
        long blk = (n4 + 255) / 256;
        if (blk > 4096) blk = 4096;
        convert_f2b<<<dim3((unsigned)blk), dim3(256), 0, stream>>>(src, dst, n4);
    };
    conv(wqkv, wqkv_b, 2560l * 2048);
    conv(wo,   wo_b,   2048l * 2048);
    convert_gu<<<dim3(4096), dim3(256), 0, stream>>>(wg, wu, wgu_b, 8388608);
    conv(wd,   wd_b,   2048l * 16384);

    rmsnorm_k<<<dim3(2048), dim3(256), 0, stream>>>(hs, ln_in, xn);
    gemm_bt<0><<<dim3(16, 20), dim3(256), 0, stream>>>(xn, wqkv_b, nullptr,
                                                       qkvf, 2048, 2560, 2048);
    qkv_post_k<<<dim3(2048, 10), dim3(256), 0, stream>>>(qkvf, cosb, sinb, kvw, qn, kn,
                                                         qbuf, kbuf, vtbuf);
    attn_k<<<dim3(16, 8, 8), dim3(256), 0, stream>>>(qbuf, kbuf, vtbuf, po, plse);
    attn_red_k<<<dim3(2048), dim3(256), 0, stream>>>(po, plse, attn_o);
    gemm_bt<1><<<dim3(16, 16), dim3(256), 0, stream>>>(attn_o, wo_b, hs,
                                                       hbuf, 2048, 2048, 2048);
    rmsnorm_k<<<dim3(2048), dim3(256), 0, stream>>>(hbuf, ln_post, x2);
    // fused gate-up: grid x = 32768/256 = 128 n-tiles, y = 8 m-tiles; 1024 threads
    gemm256<5><<<dim3(128, 8), dim3(1024), 0, stream>>>(x2, wgu_b, nullptr, actb,
                                                        2048, 16384, 2048, 1);
    // down: split-K=4 partials, then reduce with residual
    gemm256<4><<<dim3(8, 8, 4), dim3(1024), 0, stream>>>(actb, wd_b, partials, nullptr,
                                                         2048, 2048, 16384, 4);
    reduce4_k<<<dim3(2048), dim3(256), 0, stream>>>(partials, hbuf, out, 1048576);
}